// Round 5
// baseline (419.596 us; speedup 1.0000x reference)
//
#include <hip/hip_runtime.h>
#include <hip/hip_bf16.h>

#define NN 100000      // nodes
#define NR 4           // relations
#define NE 400000      // edges per relation
#define INF 128
#define HF 128
#define OUTF 64

#define WIN 16384      // histogram window (packed u16 pairs -> 32 KB LDS, 5 blocks/CU)
#define WIN2 (WIN / 2) // u32 words per histogram
#define NWIN 7         // ceil(NN / WIN)
#define SUB 16         // edge-slices per window
#define SLICE (NE / SUB)   // 25000

#define WCS 12500      // csr-build dst-window = NN/8, one window per XCD

typedef __attribute__((ext_vector_type(8))) short s16x8;   // 8 bf16 (4 VGPRs)
typedef __attribute__((ext_vector_type(4))) float f32x4;   // MFMA C/D

// ---------------- windowed LDS degree histogram (no global atomics) ------
// packed 2x16-bit counters per u32 word; int4 edge loads, 2-deep pipeline
__global__ __launch_bounds__(256) void deg_win_kernel(const int* __restrict__ src,
                                                      const int* __restrict__ dst,
                                                      unsigned int* __restrict__ parts) {
    __shared__ unsigned int hist[WIN2];
    int arr = blockIdx.z;
    int r   = blockIdx.y;
    int win = blockIdx.x / SUB;
    int sub = blockIdx.x % SUB;
    const int4* idx4 = (const int4*)((arr ? dst : src) + (size_t)r * NE + (size_t)sub * SLICE);
    int base = win * WIN;

    uint4 z4 = make_uint4(0, 0, 0, 0);
    for (int i = threadIdx.x; i < WIN2 / 4; i += 256) ((uint4*)hist)[i] = z4;
    __syncthreads();

    auto proc = [&](int4 v) {
        int a;
        a = v.x - base; if ((unsigned)a < WIN) atomicAdd(&hist[a >> 1], 1u << ((a & 1) << 4));
        a = v.y - base; if ((unsigned)a < WIN) atomicAdd(&hist[a >> 1], 1u << ((a & 1) << 4));
        a = v.z - base; if ((unsigned)a < WIN) atomicAdd(&hist[a >> 1], 1u << ((a & 1) << 4));
        a = v.w - base; if ((unsigned)a < WIN) atomicAdd(&hist[a >> 1], 1u << ((a & 1) << 4));
    };

    constexpr int NV = SLICE / 4;   // 6250 int4 per slice
    int i = threadIdx.x;
    for (; i + 256 < NV; i += 512) {
        int4 va = idx4[i];          // both loads issued before any atomic ->
        int4 vb = idx4[i + 256];    // 8 edges in flight per wave
        proc(va);
        proc(vb);
    }
    if (i < NV) proc(idx4[i]);
    __syncthreads();

    unsigned int* outp = parts + ((((size_t)arr * NR + r) * NWIN + win) * SUB + sub) * WIN2;
    for (int j = threadIdx.x; j < WIN2 / 4; j += 256)
        ((uint4*)outp)[j] = ((const uint4*)hist)[j];
}

// reduce partials -> per-rel rsqrt norms + total in-degree per dst (merged CSR)
__global__ void red_norm_kernel(const unsigned int* __restrict__ parts, int* __restrict__ deg_tot,
                                float* __restrict__ rno, float* __restrict__ rni) {
    int n = blockIdx.x * blockDim.x + threadIdx.x;
    if (n >= NN) return;
    if (n == 0) deg_tot[NN] = 0;     // sentinel so the scan yields row_ptr[NN]
    int win = n / WIN, off = n % WIN;
    int word = off >> 1, sh = (off & 1) << 4;
    int tot = 0;
    #pragma unroll
    for (int r = 0; r < NR; r++) {
        const unsigned int* p0 = parts + (((size_t)0 * NR + r) * NWIN + win) * SUB * WIN2 + word;
        const unsigned int* p1 = parts + (((size_t)1 * NR + r) * NWIN + win) * SUB * WIN2 + word;
        int so = 0, si = 0;
        #pragma unroll
        for (int s = 0; s < SUB; s++) {
            so += (p0[(size_t)s * WIN2] >> sh) & 0xFFFFu;
            si += (p1[(size_t)s * WIN2] >> sh) & 0xFFFFu;
        }
        rno[(size_t)r * NN + n] = rsqrtf(fmaxf((float)so, 1.0f));
        rni[(size_t)r * NN + n] = rsqrtf(fmaxf((float)si, 1.0f));
        tot += si;
    }
    deg_tot[n] = tot;
}

// ---------------- exclusive scan over PADDED degrees (NN+1 entries) ------
// each degree rounded up to a multiple of 8 -> branch-free 8-wide gather
__global__ void scan_block_kernel(const int* __restrict__ in, int* __restrict__ out,
                                  int* __restrict__ blockSums, int n) {
    __shared__ int sd[256];
    int t = threadIdx.x;
    int base = blockIdx.x * 1024 + t * 4;
    int v[4];
    #pragma unroll
    for (int j = 0; j < 4; j++) v[j] = (base + j < n) ? ((in[base + j] + 7) & ~7) : 0;
    int ts = v[0] + v[1] + v[2] + v[3];
    sd[t] = ts;
    __syncthreads();
    int acc = ts;
    for (int off = 1; off < 256; off <<= 1) {
        int x = (t >= off) ? sd[t - off] : 0;
        __syncthreads();
        acc += x; sd[t] = acc;
        __syncthreads();
    }
    int run = acc - ts;
    #pragma unroll
    for (int j = 0; j < 4; j++) {
        if (base + j < n) out[base + j] = run;
        run += v[j];
    }
    if (t == 255) blockSums[blockIdx.x] = acc;
}

__global__ void scan_sums_kernel(int* __restrict__ blockSums, int nb) {
    __shared__ int sd[512];
    int t = threadIdx.x;
    int v = (t < nb) ? blockSums[t] : 0;
    sd[t] = v;
    __syncthreads();
    int acc = v;
    for (int off = 1; off < 512; off <<= 1) {
        int x = (t >= off) ? sd[t - off] : 0;
        __syncthreads();
        acc += x; sd[t] = acc;
        __syncthreads();
    }
    if (t < nb) blockSums[t] = acc - v;
}

__global__ void scan_add_kernel(int* __restrict__ row_ptr, const int* __restrict__ blockSums,
                                int* __restrict__ cursor, int n) {
    int i = blockIdx.x * blockDim.x + threadIdx.x;
    if (i < n) {
        int v = row_ptr[i] + blockSums[i >> 10];
        row_ptr[i] = v;
        if (i < NN) cursor[i] = v;
    }
}

// fill pad slots [row+deg, row_ptr[n+1]) with (off=0, c=0) records
__global__ void pad_fill_kernel(const int* __restrict__ row_ptr, const int* __restrict__ deg_tot,
                                int2* __restrict__ edges) {
    int n = blockIdx.x * blockDim.x + threadIdx.x;
    if (n >= NN) return;
    int b = row_ptr[n] + deg_tot[n];
    int e = row_ptr[n + 1];
    for (int i = b; i < e; i++) edges[i] = make_int2(0, 0);
}

// ---------------- CSR build: XCD-pinned dst-windows ----------------------
// WRITE_SIZE was 8x amplified (8B records scattered from all XCDs).
// Window w = dst in [w*WCS,(w+1)*WCS) handled ONLY by blocks with
// blockIdx&7==w (round-robin XCD mapping, locality heuristic): window's
// 2MB edge region + 50KB cursors stay in ONE XCD's L2 -> lines written once.
// Cost: each (rel,slice) re-scanned 8x (src/dst 12.8MB total, L3-resident).
__global__ __launch_bounds__(256) void csr_build_kernel(const int* __restrict__ src,
                                 const int* __restrict__ dst,
                                 const float* __restrict__ rno, const float* __restrict__ rni,
                                 int* __restrict__ cursor, int2* __restrict__ edges) {
    int b   = blockIdx.x;
    int w   = b & 7;            // dst-window == target XCD
    int k   = b >> 3;           // 0..63 slice id
    int r   = k >> 4;           // relation
    int sub = k & 15;           // slice within relation
    int base = w * WCS;

    const int4* sp4 = (const int4*)(src + (size_t)r * NE + (size_t)sub * SLICE);
    const int4* dp4 = (const int4*)(dst + (size_t)r * NE + (size_t)sub * SLICE);

    auto one = [&](int s, int d) {
        if ((unsigned)(d - base) < WCS) {
            int pos = atomicAdd(&cursor[d], 1);
            float c = rno[(size_t)r * NN + s] * rni[(size_t)r * NN + d];
            edges[pos] = make_int2((r * NN + s) << 8, __float_as_int(c));
        }
    };

    constexpr int NV = SLICE / 4;   // 6250
    for (int i = threadIdx.x; i < NV; i += 256) {
        int4 d4 = dp4[i];
        int4 s4 = sp4[i];
        one(s4.x, d4.x);
        one(s4.y, d4.y);
        one(s4.z, d4.z);
        one(s4.w, d4.w);
    }
}

// fused: Wt transpose-cast (blocks 0..383) + bias sums (block 384)
__global__ void prep_kernel(const float* __restrict__ W1, const float* __restrict__ W2,
                            const float* __restrict__ b1, const float* __restrict__ b2,
                            __hip_bfloat16* __restrict__ Wt1, __hip_bfloat16* __restrict__ Wt2,
                            float* __restrict__ bsum1, float* __restrict__ bsum2) {
    if (blockIdx.x == 384) {
        int t = threadIdx.x;
        if (t < HF) {
            float s = 0.f;
            for (int r = 0; r < NR; r++) s += b1[r * HF + t];
            bsum1[t] = s;
        } else if (t < HF + OUTF) {
            int f = t - HF;
            float s = 0.f;
            for (int r = 0; r < NR; r++) s += b2[r * OUTF + f];
            bsum2[f] = s;
        }
        return;
    }
    int id = blockIdx.x * 256 + threadIdx.x;
    if (id < NR * HF * INF) {
        int r = id >> 14, rem = id & 16383;
        int n_ = rem >> 7, k = rem & 127;
        Wt1[id] = __float2bfloat16(W1[((size_t)r * INF + k) * HF + n_]);
    } else {
        int id2 = id - NR * HF * INF;
        if (id2 < NR * OUTF * HF) {
            int r = id2 >> 13, rem = id2 & 8191;
            int n_ = rem >> 7, k = rem & 127;
            Wt2[id2] = __float2bfloat16(W2[((size_t)r * HF + k) * OUTF + n_]);
        }
    }
}

__device__ __forceinline__ s16x8 pack_bf16x8(float4 a0, float4 a1) {
    union { s16x8 v; __hip_bfloat162 h[4]; } u;
    u.h[0] = __float22bfloat162_rn(make_float2(a0.x, a0.y));
    u.h[1] = __float22bfloat162_rn(make_float2(a0.z, a0.w));
    u.h[2] = __float22bfloat162_rn(make_float2(a1.x, a1.y));
    u.h[3] = __float22bfloat162_rn(make_float2(a1.z, a1.w));
    return u.v;
}

__device__ __forceinline__ void load_lds_16(const void* g, void* l) {
    __builtin_amdgcn_global_load_lds(
        (const __attribute__((address_space(1))) void*)g,
        (__attribute__((address_space(3))) void*)l, 16, 0, 0);
}

// ---------------- bf16 MFMA GEMM, A-reuse over relations ------------------
// Zb[rel][N][F] = A[N,128] @ Wt[rel][F,128]^T for rel in [0, nrel)
// - W[rel] staged in LDS via global_load_lds (pre-swizzled source) ->
//   conflict-free stride-256B ds_read_b128 fragment reads
// - swapped MFMA operands: lane holds 4 consecutive features of one node ->
//   direct 8B global stores, no LDS store staging
template<int F, typename AT>
__global__ __launch_bounds__(256, 3) void gemm_all(const AT* __restrict__ Xb,
                                                   const __hip_bfloat16* __restrict__ Wt,
                                                   __hip_bfloat16* __restrict__ Zb, int nrel) {
    constexpr int NT = F / 16;          // feature tiles of 16
    constexpr int NG = F * 16;          // 16B granules in Bs (F rows * 256B / 16)
    __shared__ __attribute__((aligned(16))) __hip_bfloat16 Bs[F * 128];

    int tid  = threadIdx.x;
    int wid  = tid >> 6;
    int lane = tid & 63;
    int quad = lane >> 4;
    int l16  = lane & 15;
    int sw   = l16 & 7;                 // per-lane read swizzle (row & 7)

    int mbase = blockIdx.x * 128;

    int bofs[4];
    #pragma unroll
    for (int kb = 0; kb < 4; kb++)
        bofs[kb] = l16 * 256 + (((kb * 4 + quad) ^ sw) << 4);

    // A fragments: 2 row-tiles of 16 nodes each, K=128 (4 kb of 32)
    s16x8 afr[2][4];
    #pragma unroll
    for (int mt = 0; mt < 2; mt++) {
        int mrow = mbase + mt * 64 + wid * 16 + l16;
        if (mrow >= NN) mrow = NN - 1;
        #pragma unroll
        for (int kb = 0; kb < 4; kb++) {
            if constexpr (sizeof(AT) == 4) {
                const float* xr = (const float*)Xb + (size_t)mrow * 128 + kb * 32 + quad * 8;
                float4 a0 = *(const float4*)xr;
                float4 a1 = *(const float4*)(xr + 4);
                afr[mt][kb] = pack_bf16x8(a0, a1);
            } else {
                afr[mt][kb] = *(const s16x8*)((const __hip_bfloat16*)Xb + (size_t)mrow * 128 + kb * 32 + quad * 8);
            }
        }
    }

    for (int rel = 0; rel < nrel; rel++) {
        if (rel) __syncthreads();       // all waves done reading Bs of prev rel

        {
            const char* W = (const char*)(Wt + (size_t)rel * F * 128);
            #pragma unroll
            for (int it = 0; it < NG / 256; it++) {
                int dg = it * 256 + tid;              // dest granule (linear)
                int sg = dg ^ ((dg >> 4) & 7);        // source granule (inverse swz)
                load_lds_16(W + (size_t)sg * 16, (char*)Bs + (size_t)(dg & ~63) * 16);
            }
        }
        __syncthreads();                // drains vmcnt -> Bs ready

        __hip_bfloat16* Z = Zb + (size_t)rel * NN * F;

        f32x4 acc[2][NT];
        #pragma unroll
        for (int nt = 0; nt < NT; nt++) {
            acc[0][nt] = (f32x4){0.f, 0.f, 0.f, 0.f};
            acc[1][nt] = (f32x4){0.f, 0.f, 0.f, 0.f};
            #pragma unroll
            for (int kb = 0; kb < 4; kb++) {
                s16x8 bfr = *(const s16x8*)((const char*)Bs + nt * 4096 + bofs[kb]);
                acc[0][nt] = __builtin_amdgcn_mfma_f32_16x16x32_bf16(bfr, afr[0][kb], acc[0][nt], 0, 0, 0);
                acc[1][nt] = __builtin_amdgcn_mfma_f32_16x16x32_bf16(bfr, afr[1][kb], acc[1][nt], 0, 0, 0);
            }
        }

        #pragma unroll
        for (int mt = 0; mt < 2; mt++) {
            int g = mbase + mt * 64 + wid * 16 + l16;
            if (g < NN) {
                #pragma unroll
                for (int nt = 0; nt < NT; nt++) {
                    union { uint2 u; __hip_bfloat162 h[2]; } o;
                    o.h[0] = __float22bfloat162_rn(make_float2(acc[mt][nt][0], acc[mt][nt][1]));
                    o.h[1] = __float22bfloat162_rn(make_float2(acc[mt][nt][2], acc[mt][nt][3]));
                    *(uint2*)(Z + (size_t)g * F + nt * 16 + quad * 4) = o.u;
                }
            }
        }
    }
}

// ---------------- merged-CSR gather: branch-free 8-wide (padded segments) -
// edge.x = (rel*NN+src)*256 byte offset into Zb (F=128); >>1 for F=64
template<int F, bool RELU, bool OUT_F32>
__global__ __launch_bounds__(256) void gather_merged(const int* __restrict__ row_ptr,
                              const int2* __restrict__ edges,
                              const __hip_bfloat16* __restrict__ Zb,
                              float* __restrict__ outf, __hip_bfloat16* __restrict__ outb,
                              const float* __restrict__ bsum) {
    int wid  = threadIdx.x >> 6;
    int lane = threadIdx.x & 63;
    int n = blockIdx.x * 4 + wid;          // NN % 4 == 0 -> exact cover
    int beg = row_ptr[n];
    int end = row_ptr[n + 1];

    if constexpr (F == 128) {
        const char* Zl = (const char*)Zb + lane * 4;
        float2 a = *(const float2*)(bsum + lane * 2);
        for (int p = beg; p < end; p += 8) {
            int2 e[8];
            #pragma unroll
            for (int j = 0; j < 8; j++) e[j] = edges[p + j];
            float2 zz[8];
            #pragma unroll
            for (int j = 0; j < 8; j++)
                zz[j] = __bfloat1622float2(*(const __hip_bfloat162*)(Zl + e[j].x));
            #pragma unroll
            for (int j = 0; j < 8; j++) {
                float c = __int_as_float(e[j].y);
                a.x = fmaf(c, zz[j].x, a.x);
                a.y = fmaf(c, zz[j].y, a.y);
            }
        }
        if constexpr (RELU) { a.x = fmaxf(a.x, 0.f); a.y = fmaxf(a.y, 0.f); }
        *(__hip_bfloat162*)(outb + (size_t)n * 128 + lane * 2) = __float22bfloat162_rn(a);
    } else {
        const char* Zl = (const char*)Zb + lane * 2;
        float a = bsum[lane];
        for (int p = beg; p < end; p += 8) {
            int2 e[8];
            #pragma unroll
            for (int j = 0; j < 8; j++) e[j] = edges[p + j];
            float zz[8];
            #pragma unroll
            for (int j = 0; j < 8; j++)
                zz[j] = __bfloat162float(*(const __hip_bfloat16*)(Zl + (e[j].x >> 1)));
            #pragma unroll
            for (int j = 0; j < 8; j++) a = fmaf(__int_as_float(e[j].y), zz[j], a);
        }
        if constexpr (RELU) a = fmaxf(a, 0.f);
        if constexpr (OUT_F32) outf[(size_t)n * 64 + lane] = a;
        else outb[(size_t)n * 64 + lane] = __float2bfloat16(a);
    }
}

extern "C" void kernel_launch(void* const* d_in, const int* in_sizes, int n_in,
                              void* d_out, int out_size, void* d_ws, size_t ws_size,
                              hipStream_t stream) {
    const float* x   = (const float*)d_in[0];
    const int*   src = (const int*)  d_in[1];   // [4, 400000]
    const int*   dst = (const int*)  d_in[2];
    const float* W1  = (const float*)d_in[3];   // [4,128,128]
    const float* b1  = (const float*)d_in[4];   // [4,128]
    const float* W2  = (const float*)d_in[5];   // [4,128,64]
    const float* b2  = (const float*)d_in[6];   // [4,64]
    float* out = (float*)d_out;                 // [100000,64] fp32

    constexpr int RN = NR * NN;                 // 400000 (norm arrays)
    constexpr int NSC = NN + 1;                 // scan covers NN+1 entries
    constexpr int NB = (NSC + 1023) / 1024;     // 98 scan blocks

    char* p = (char*)d_ws;
    int*   deg_tot   = (int*)p;   p += ((size_t)NN + 16) * 4;
    float* rno       = (float*)p; p += (size_t)RN * 4;
    float* rni       = (float*)p; p += (size_t)RN * 4;
    int*   row_ptr   = (int*)p;   p += ((size_t)NN + 16) * 4;
    int*   cursor    = (int*)p;   p += (size_t)NN * 4;
    int*   blockSums = (int*)p;   p += 1024 * 4;
    int2*  edges     = (int2*)p;  p += ((size_t)NR * NE + 8 * NN) * 8;   // 19.2 MB (padded)
    float* bsum1 = (float*)p; p += HF * 4;
    float* bsum2 = (float*)p; p += OUTF * 4;
    __hip_bfloat16* hb  = (__hip_bfloat16*)p; p += (size_t)NN * HF * 2;    // 25.6 MB
    __hip_bfloat16* Wt1 = (__hip_bfloat16*)p; p += (size_t)NR * HF * INF * 2;
    __hip_bfloat16* Wt2 = (__hip_bfloat16*)p; p += (size_t)NR * OUTF * HF * 2;
    __hip_bfloat16* Zb = (__hip_bfloat16*)p;  // 4 rels: 102.4 MB
    // parts aliases Zb (dead before any GEMM writes): 29.4 MB
    unsigned int* parts = (unsigned int*)Zb;

    // ---- CSR build (merged dst-keyed list, 8-padded segments) ----
    prep_kernel<<<385, 256, 0, stream>>>(W1, W2, b1, b2, Wt1, Wt2, bsum1, bsum2);
    deg_win_kernel<<<dim3(NWIN * SUB, NR, 2), 256, 0, stream>>>(src, dst, parts);
    red_norm_kernel<<<(NN + 255) / 256, 256, 0, stream>>>(parts, deg_tot, rno, rni);
    scan_block_kernel<<<NB, 256, 0, stream>>>(deg_tot, row_ptr, blockSums, NSC);
    scan_sums_kernel<<<1, 512, 0, stream>>>(blockSums, NB);
    scan_add_kernel<<<(NSC + 255) / 256, 256, 0, stream>>>(row_ptr, blockSums, cursor, NSC);
    pad_fill_kernel<<<(NN + 255) / 256, 256, 0, stream>>>(row_ptr, deg_tot, edges);
    csr_build_kernel<<<512, 256, 0, stream>>>(src, dst, rno, rni, cursor, edges);

    constexpr int GB = (NN + 127) / 128;  // 782 blocks, 128 rows each
    constexpr int GG = NN / 4;            // 25000

    // ---- layer 1: 4-rel A-reuse GEMM + ONE merged gather (bias+relu fused) ----
    gemm_all<HF, float><<<GB, 256, 0, stream>>>(x, Wt1, Zb, 4);
    gather_merged<HF, true, false><<<GG, 256, 0, stream>>>(
        row_ptr, edges, Zb, nullptr, hb, bsum1);

    // ---- layer 2: 4-rel A-reuse GEMM + ONE merged gather ----
    gemm_all<OUTF, __hip_bfloat16><<<GB, 256, 0, stream>>>(hb, Wt2, Zb, 4);
    gather_merged<OUTF, false, true><<<GG, 256, 0, stream>>>(
        row_ptr, edges, Zb, out, nullptr, bsum2);
}

// Round 6
// 367.859 us; speedup vs baseline: 1.1406x; 1.1406x over previous
//
#include <hip/hip_runtime.h>
#include <hip/hip_bf16.h>

#define NN 100000      // nodes
#define NR 4           // relations
#define NE 400000      // edges per relation
#define INF 128
#define HF 128
#define OUTF 64

#define WIN 16384      // histogram window (packed u16 pairs -> 32 KB LDS, 5 blocks/CU)
#define WIN2 (WIN / 2) // u32 words per histogram
#define NWIN 7         // ceil(NN / WIN)
#define SUB 16         // edge-slices per window
#define SLICE (NE / SUB)   // 25000

#define GB 782         // gemm blocks (128 rows each)
#define CB 1563        // csr blocks per relation ((NE+255)/256)
#define CSRB (NR * CB) // 6252
#define PADB 391       // pad blocks ((NN+255)/256)
#define FGRID (GB + CSRB + PADB)   // 7425 fused grid

typedef __attribute__((ext_vector_type(8))) short s16x8;   // 8 bf16 (4 VGPRs)
typedef __attribute__((ext_vector_type(4))) float f32x4;   // MFMA C/D

// ---------------- windowed LDS degree histogram (no global atomics) ------
// packed 2x16-bit counters per u32 word; int4 edge loads, 2-deep pipeline
__global__ __launch_bounds__(256) void deg_win_kernel(const int* __restrict__ src,
                                                      const int* __restrict__ dst,
                                                      unsigned int* __restrict__ parts) {
    __shared__ unsigned int hist[WIN2];
    int arr = blockIdx.z;
    int r   = blockIdx.y;
    int win = blockIdx.x / SUB;
    int sub = blockIdx.x % SUB;
    const int4* idx4 = (const int4*)((arr ? dst : src) + (size_t)r * NE + (size_t)sub * SLICE);
    int base = win * WIN;

    uint4 z4 = make_uint4(0, 0, 0, 0);
    for (int i = threadIdx.x; i < WIN2 / 4; i += 256) ((uint4*)hist)[i] = z4;
    __syncthreads();

    auto proc = [&](int4 v) {
        int a;
        a = v.x - base; if ((unsigned)a < WIN) atomicAdd(&hist[a >> 1], 1u << ((a & 1) << 4));
        a = v.y - base; if ((unsigned)a < WIN) atomicAdd(&hist[a >> 1], 1u << ((a & 1) << 4));
        a = v.z - base; if ((unsigned)a < WIN) atomicAdd(&hist[a >> 1], 1u << ((a & 1) << 4));
        a = v.w - base; if ((unsigned)a < WIN) atomicAdd(&hist[a >> 1], 1u << ((a & 1) << 4));
    };

    constexpr int NV = SLICE / 4;   // 6250 int4 per slice
    int i = threadIdx.x;
    for (; i + 256 < NV; i += 512) {
        int4 va = idx4[i];          // both loads issued before any atomic ->
        int4 vb = idx4[i + 256];    // 8 edges in flight per wave
        proc(va);
        proc(vb);
    }
    if (i < NV) proc(idx4[i]);
    __syncthreads();

    unsigned int* outp = parts + ((((size_t)arr * NR + r) * NWIN + win) * SUB + sub) * WIN2;
    for (int j = threadIdx.x; j < WIN2 / 4; j += 256)
        ((uint4*)outp)[j] = ((const uint4*)hist)[j];
}

// reduce partials -> per-rel rsqrt norms + total in-degree per dst (merged CSR)
__global__ void red_norm_kernel(const unsigned int* __restrict__ parts, int* __restrict__ deg_tot,
                                float* __restrict__ rno, float* __restrict__ rni) {
    int n = blockIdx.x * blockDim.x + threadIdx.x;
    if (n >= NN) return;
    if (n == 0) deg_tot[NN] = 0;     // sentinel so the scan yields row_ptr[NN]
    int win = n / WIN, off = n % WIN;
    int word = off >> 1, sh = (off & 1) << 4;
    int tot = 0;
    #pragma unroll
    for (int r = 0; r < NR; r++) {
        const unsigned int* p0 = parts + (((size_t)0 * NR + r) * NWIN + win) * SUB * WIN2 + word;
        const unsigned int* p1 = parts + (((size_t)1 * NR + r) * NWIN + win) * SUB * WIN2 + word;
        int so = 0, si = 0;
        #pragma unroll
        for (int s = 0; s < SUB; s++) {
            so += (p0[(size_t)s * WIN2] >> sh) & 0xFFFFu;
            si += (p1[(size_t)s * WIN2] >> sh) & 0xFFFFu;
        }
        rno[(size_t)r * NN + n] = rsqrtf(fmaxf((float)so, 1.0f));
        rni[(size_t)r * NN + n] = rsqrtf(fmaxf((float)si, 1.0f));
        tot += si;
    }
    deg_tot[n] = tot;
}

// ---------------- exclusive scan over PADDED degrees (NN+1 entries) ------
// each degree rounded up to a multiple of 8 -> branch-free 8-wide gather
__global__ void scan_block_kernel(const int* __restrict__ in, int* __restrict__ out,
                                  int* __restrict__ blockSums, int n) {
    __shared__ int sd[256];
    int t = threadIdx.x;
    int base = blockIdx.x * 1024 + t * 4;
    int v[4];
    #pragma unroll
    for (int j = 0; j < 4; j++) v[j] = (base + j < n) ? ((in[base + j] + 7) & ~7) : 0;
    int ts = v[0] + v[1] + v[2] + v[3];
    sd[t] = ts;
    __syncthreads();
    int acc = ts;
    for (int off = 1; off < 256; off <<= 1) {
        int x = (t >= off) ? sd[t - off] : 0;
        __syncthreads();
        acc += x; sd[t] = acc;
        __syncthreads();
    }
    int run = acc - ts;
    #pragma unroll
    for (int j = 0; j < 4; j++) {
        if (base + j < n) out[base + j] = run;
        run += v[j];
    }
    if (t == 255) blockSums[blockIdx.x] = acc;
}

__global__ void scan_sums_kernel(int* __restrict__ blockSums, int nb) {
    __shared__ int sd[512];
    int t = threadIdx.x;
    int v = (t < nb) ? blockSums[t] : 0;
    sd[t] = v;
    __syncthreads();
    int acc = v;
    for (int off = 1; off < 512; off <<= 1) {
        int x = (t >= off) ? sd[t - off] : 0;
        __syncthreads();
        acc += x; sd[t] = acc;
        __syncthreads();
    }
    if (t < nb) blockSums[t] = acc - v;
}

__global__ void scan_add_kernel(int* __restrict__ row_ptr, const int* __restrict__ blockSums,
                                int* __restrict__ cursor, int n) {
    int i = blockIdx.x * blockDim.x + threadIdx.x;
    if (i < n) {
        int v = row_ptr[i] + blockSums[i >> 10];
        row_ptr[i] = v;
        if (i < NN) cursor[i] = v;
    }
}

// fused: Wt transpose-cast (blocks 0..383) + bias sums (block 384)
__global__ void prep_kernel(const float* __restrict__ W1, const float* __restrict__ W2,
                            const float* __restrict__ b1, const float* __restrict__ b2,
                            __hip_bfloat16* __restrict__ Wt1, __hip_bfloat16* __restrict__ Wt2,
                            float* __restrict__ bsum1, float* __restrict__ bsum2) {
    if (blockIdx.x == 384) {
        int t = threadIdx.x;
        if (t < HF) {
            float s = 0.f;
            for (int r = 0; r < NR; r++) s += b1[r * HF + t];
            bsum1[t] = s;
        } else if (t < HF + OUTF) {
            int f = t - HF;
            float s = 0.f;
            for (int r = 0; r < NR; r++) s += b2[r * OUTF + f];
            bsum2[f] = s;
        }
        return;
    }
    int id = blockIdx.x * 256 + threadIdx.x;
    if (id < NR * HF * INF) {
        int r = id >> 14, rem = id & 16383;
        int n_ = rem >> 7, k = rem & 127;
        Wt1[id] = __float2bfloat16(W1[((size_t)r * INF + k) * HF + n_]);
    } else {
        int id2 = id - NR * HF * INF;
        if (id2 < NR * OUTF * HF) {
            int r = id2 >> 13, rem = id2 & 8191;
            int n_ = rem >> 7, k = rem & 127;
            Wt2[id2] = __float2bfloat16(W2[((size_t)r * HF + k) * OUTF + n_]);
        }
    }
}

__device__ __forceinline__ s16x8 pack_bf16x8(float4 a0, float4 a1) {
    union { s16x8 v; __hip_bfloat162 h[4]; } u;
    u.h[0] = __float22bfloat162_rn(make_float2(a0.x, a0.y));
    u.h[1] = __float22bfloat162_rn(make_float2(a0.z, a0.w));
    u.h[2] = __float22bfloat162_rn(make_float2(a1.x, a1.y));
    u.h[3] = __float22bfloat162_rn(make_float2(a1.z, a1.w));
    return u.v;
}

__device__ __forceinline__ void load_lds_16(const void* g, void* l) {
    __builtin_amdgcn_global_load_lds(
        (const __attribute__((address_space(1))) void*)g,
        (__attribute__((address_space(3))) void*)l, 16, 0, 0);
}

// ---------------- bf16 MFMA GEMM body, A-reuse over relations -------------
// Zb[rel][N][F] = A[N,128] @ Wt[rel][F,128]^T for rel in [0, nrel)
// - W[rel] staged in LDS via global_load_lds (pre-swizzled source) ->
//   conflict-free stride-256B ds_read_b128 fragment reads
// - swapped MFMA operands: lane holds 4 consecutive features of one node ->
//   direct 8B global stores, no LDS store staging
template<int F, typename AT>
__device__ __forceinline__ void gemm_body(int mbase, const AT* __restrict__ Xb,
                                          const __hip_bfloat16* __restrict__ Wt,
                                          __hip_bfloat16* __restrict__ Zb, int nrel,
                                          __hip_bfloat16* Bs) {
    constexpr int NT = F / 16;          // feature tiles of 16
    constexpr int NG = F * 16;          // 16B granules in Bs (F rows * 256B / 16)

    int tid  = threadIdx.x;
    int wid  = tid >> 6;
    int lane = tid & 63;
    int quad = lane >> 4;
    int l16  = lane & 15;
    int sw   = l16 & 7;                 // per-lane read swizzle (row & 7)

    int bofs[4];
    #pragma unroll
    for (int kb = 0; kb < 4; kb++)
        bofs[kb] = l16 * 256 + (((kb * 4 + quad) ^ sw) << 4);

    // A fragments: 2 row-tiles of 16 nodes each, K=128 (4 kb of 32)
    s16x8 afr[2][4];
    #pragma unroll
    for (int mt = 0; mt < 2; mt++) {
        int mrow = mbase + mt * 64 + wid * 16 + l16;
        if (mrow >= NN) mrow = NN - 1;
        #pragma unroll
        for (int kb = 0; kb < 4; kb++) {
            if constexpr (sizeof(AT) == 4) {
                const float* xr = (const float*)Xb + (size_t)mrow * 128 + kb * 32 + quad * 8;
                float4 a0 = *(const float4*)xr;
                float4 a1 = *(const float4*)(xr + 4);
                afr[mt][kb] = pack_bf16x8(a0, a1);
            } else {
                afr[mt][kb] = *(const s16x8*)((const __hip_bfloat16*)Xb + (size_t)mrow * 128 + kb * 32 + quad * 8);
            }
        }
    }

    for (int rel = 0; rel < nrel; rel++) {
        if (rel) __syncthreads();       // all waves done reading Bs of prev rel

        {
            const char* W = (const char*)(Wt + (size_t)rel * F * 128);
            #pragma unroll
            for (int it = 0; it < NG / 256; it++) {
                int dg = it * 256 + tid;              // dest granule (linear)
                int sg = dg ^ ((dg >> 4) & 7);        // source granule (inverse swz)
                load_lds_16(W + (size_t)sg * 16, (char*)Bs + (size_t)(dg & ~63) * 16);
            }
        }
        __syncthreads();                // drains vmcnt -> Bs ready

        __hip_bfloat16* Z = Zb + (size_t)rel * NN * F;

        f32x4 acc[2][NT];
        #pragma unroll
        for (int nt = 0; nt < NT; nt++) {
            acc[0][nt] = (f32x4){0.f, 0.f, 0.f, 0.f};
            acc[1][nt] = (f32x4){0.f, 0.f, 0.f, 0.f};
            #pragma unroll
            for (int kb = 0; kb < 4; kb++) {
                s16x8 bfr = *(const s16x8*)((const char*)Bs + nt * 4096 + bofs[kb]);
                acc[0][nt] = __builtin_amdgcn_mfma_f32_16x16x32_bf16(bfr, afr[0][kb], acc[0][nt], 0, 0, 0);
                acc[1][nt] = __builtin_amdgcn_mfma_f32_16x16x32_bf16(bfr, afr[1][kb], acc[1][nt], 0, 0, 0);
            }
        }

        #pragma unroll
        for (int mt = 0; mt < 2; mt++) {
            int g = mbase + mt * 64 + wid * 16 + l16;
            if (g < NN) {
                #pragma unroll
                for (int nt = 0; nt < NT; nt++) {
                    union { uint2 u; __hip_bfloat162 h[2]; } o;
                    o.h[0] = __float22bfloat162_rn(make_float2(acc[mt][nt][0], acc[mt][nt][1]));
                    o.h[1] = __float22bfloat162_rn(make_float2(acc[mt][nt][2], acc[mt][nt][3]));
                    *(uint2*)(Z + (size_t)g * F + nt * 16 + quad * 4) = o.u;
                }
            }
        }
    }
}

// ---------------- FUSED: gemm1 (1-in-3 stripe) || csr_build || pad_fill ---
// Independent work co-resident: GEMM is MFMA/LDS-bound, csr is scatter-write
// BW-bound (R5: sustains ~1.9 TB/s at 20% occupancy) -> disjoint resources.
// Stream order guarantees deps: scan_add/red_norm before; gather1 after.
__global__ __launch_bounds__(256, 3) void fused1_kernel(
        const float* __restrict__ x, const __hip_bfloat16* __restrict__ Wt1,
        __hip_bfloat16* __restrict__ Zb,
        const int* __restrict__ src, const int* __restrict__ dst,
        const float* __restrict__ rno, const float* __restrict__ rni,
        int* __restrict__ cursor, int2* __restrict__ edges,
        const int* __restrict__ row_ptr, const int* __restrict__ deg_tot) {
    __shared__ __attribute__((aligned(16))) __hip_bfloat16 Bs[HF * 128];
    int b = blockIdx.x;
    bool isg = (b % 3 == 1) && (b / 3 < GB);
    if (isg) {
        gemm_body<HF, float>((b / 3) * 128, x, Wt1, Zb, NR, Bs);
        return;
    }
    int cnt = (b <= 1) ? 0 : ((b + 1) / 3);          // gemm blocks before b
    if (cnt > GB) cnt = GB;
    int ng = b - cnt;                                 // 0..6642
    if (ng < CSRB) {
        // ---- csr build (R4 form): dst-keyed merged list, byte-offset records
        int r = ng / CB;
        int i = (ng % CB) * 256 + threadIdx.x;
        if (i < NE) {
            int s = src[(size_t)r * NE + i];
            int d = dst[(size_t)r * NE + i];
            int pos = atomicAdd(&cursor[d], 1);
            float c = rno[(size_t)r * NN + s] * rni[(size_t)r * NN + d];
            edges[pos] = make_int2((r * NN + s) << 8, __float_as_int(c));
        }
    } else {
        // ---- pad fill: slots [row+deg, row_ptr[n+1]) <- (off=0, c=0)
        int n = (ng - CSRB) * 256 + threadIdx.x;
        if (n < NN) {
            int pb = row_ptr[n] + deg_tot[n];
            int pe = row_ptr[n + 1];
            for (int i = pb; i < pe; i++) edges[i] = make_int2(0, 0);
        }
    }
}

// standalone GEMM for layer 2
template<int F, typename AT>
__global__ __launch_bounds__(256, 3) void gemm_all(const AT* __restrict__ Xb,
                                                   const __hip_bfloat16* __restrict__ Wt,
                                                   __hip_bfloat16* __restrict__ Zb, int nrel) {
    __shared__ __attribute__((aligned(16))) __hip_bfloat16 Bs[F * 128];
    gemm_body<F, AT>(blockIdx.x * 128, Xb, Wt, Zb, nrel, Bs);
}

// ---------------- merged-CSR gather: branch-free 8-wide (padded segments) -
// edge.x = (rel*NN+src)*256 byte offset into Zb (F=128); >>1 for F=64
template<int F, bool RELU, bool OUT_F32>
__global__ __launch_bounds__(256) void gather_merged(const int* __restrict__ row_ptr,
                              const int2* __restrict__ edges,
                              const __hip_bfloat16* __restrict__ Zb,
                              float* __restrict__ outf, __hip_bfloat16* __restrict__ outb,
                              const float* __restrict__ bsum) {
    int wid  = threadIdx.x >> 6;
    int lane = threadIdx.x & 63;
    int n = blockIdx.x * 4 + wid;          // NN % 4 == 0 -> exact cover
    int beg = row_ptr[n];
    int end = row_ptr[n + 1];

    if constexpr (F == 128) {
        const char* Zl = (const char*)Zb + lane * 4;
        float2 a = *(const float2*)(bsum + lane * 2);
        for (int p = beg; p < end; p += 8) {
            int2 e[8];
            #pragma unroll
            for (int j = 0; j < 8; j++) e[j] = edges[p + j];
            float2 zz[8];
            #pragma unroll
            for (int j = 0; j < 8; j++)
                zz[j] = __bfloat1622float2(*(const __hip_bfloat162*)(Zl + e[j].x));
            #pragma unroll
            for (int j = 0; j < 8; j++) {
                float c = __int_as_float(e[j].y);
                a.x = fmaf(c, zz[j].x, a.x);
                a.y = fmaf(c, zz[j].y, a.y);
            }
        }
        if constexpr (RELU) { a.x = fmaxf(a.x, 0.f); a.y = fmaxf(a.y, 0.f); }
        *(__hip_bfloat162*)(outb + (size_t)n * 128 + lane * 2) = __float22bfloat162_rn(a);
    } else {
        const char* Zl = (const char*)Zb + lane * 2;
        float a = bsum[lane];
        for (int p = beg; p < end; p += 8) {
            int2 e[8];
            #pragma unroll
            for (int j = 0; j < 8; j++) e[j] = edges[p + j];
            float zz[8];
            #pragma unroll
            for (int j = 0; j < 8; j++)
                zz[j] = __bfloat162float(*(const __hip_bfloat16*)(Zl + (e[j].x >> 1)));
            #pragma unroll
            for (int j = 0; j < 8; j++) a = fmaf(__int_as_float(e[j].y), zz[j], a);
        }
        if constexpr (RELU) a = fmaxf(a, 0.f);
        if constexpr (OUT_F32) outf[(size_t)n * 64 + lane] = a;
        else outb[(size_t)n * 64 + lane] = __float2bfloat16(a);
    }
}

extern "C" void kernel_launch(void* const* d_in, const int* in_sizes, int n_in,
                              void* d_out, int out_size, void* d_ws, size_t ws_size,
                              hipStream_t stream) {
    const float* x   = (const float*)d_in[0];
    const int*   src = (const int*)  d_in[1];   // [4, 400000]
    const int*   dst = (const int*)  d_in[2];
    const float* W1  = (const float*)d_in[3];   // [4,128,128]
    const float* b1  = (const float*)d_in[4];   // [4,128]
    const float* W2  = (const float*)d_in[5];   // [4,128,64]
    const float* b2  = (const float*)d_in[6];   // [4,64]
    float* out = (float*)d_out;                 // [100000,64] fp32

    constexpr int RN = NR * NN;                 // 400000 (norm arrays)
    constexpr int NSC = NN + 1;                 // scan covers NN+1 entries
    constexpr int NB = (NSC + 1023) / 1024;     // 98 scan blocks

    char* p = (char*)d_ws;
    int*   deg_tot   = (int*)p;   p += ((size_t)NN + 16) * 4;
    float* rno       = (float*)p; p += (size_t)RN * 4;
    float* rni       = (float*)p; p += (size_t)RN * 4;
    int*   row_ptr   = (int*)p;   p += ((size_t)NN + 16) * 4;
    int*   cursor    = (int*)p;   p += (size_t)NN * 4;
    int*   blockSums = (int*)p;   p += 1024 * 4;
    int2*  edges     = (int2*)p;  p += ((size_t)NR * NE + 8 * NN) * 8;   // 19.2 MB (padded)
    float* bsum1 = (float*)p; p += HF * 4;
    float* bsum2 = (float*)p; p += OUTF * 4;
    __hip_bfloat16* hb  = (__hip_bfloat16*)p; p += (size_t)NN * HF * 2;    // 25.6 MB
    __hip_bfloat16* Wt1 = (__hip_bfloat16*)p; p += (size_t)NR * HF * INF * 2;
    __hip_bfloat16* Wt2 = (__hip_bfloat16*)p; p += (size_t)NR * OUTF * HF * 2;
    __hip_bfloat16* Zb = (__hip_bfloat16*)p;  // 4 rels: 102.4 MB
    // parts aliases Zb (dead before any GEMM writes): 29.4 MB
    unsigned int* parts = (unsigned int*)Zb;

    // ---- front-end: norms + padded scan (cursor/row_ptr ready) ----
    prep_kernel<<<385, 256, 0, stream>>>(W1, W2, b1, b2, Wt1, Wt2, bsum1, bsum2);
    deg_win_kernel<<<dim3(NWIN * SUB, NR, 2), 256, 0, stream>>>(src, dst, parts);
    red_norm_kernel<<<(NN + 255) / 256, 256, 0, stream>>>(parts, deg_tot, rno, rni);
    scan_block_kernel<<<NB, 256, 0, stream>>>(deg_tot, row_ptr, blockSums, NSC);
    scan_sums_kernel<<<1, 512, 0, stream>>>(blockSums, NB);
    scan_add_kernel<<<(NSC + 255) / 256, 256, 0, stream>>>(row_ptr, blockSums, cursor, NSC);

    // ---- fused: layer-1 GEMM || csr build || pad fill (all independent) ----
    fused1_kernel<<<FGRID, 256, 0, stream>>>(x, Wt1, Zb, src, dst, rno, rni,
                                             cursor, edges, row_ptr, deg_tot);

    constexpr int GG = NN / 4;            // 25000

    // ---- layer 1 gather (bias+relu fused) ----
    gather_merged<HF, true, false><<<GG, 256, 0, stream>>>(
        row_ptr, edges, Zb, nullptr, hb, bsum1);

    // ---- layer 2: 4-rel A-reuse GEMM + ONE merged gather ----
    gemm_all<OUTF, __hip_bfloat16><<<GB, 256, 0, stream>>>(hb, Wt2, Zb, 4);
    gather_merged<OUTF, false, true><<<GG, 256, 0, stream>>>(
        row_ptr, edges, Zb, out, nullptr, bsum2);
}